// Round 3
// baseline (169.927 us; speedup 1.0000x reference)
//
#include <hip/hip_runtime.h>
#include <hip/hip_bf16.h>

// QuIP#-style quantized linear. bf16 MFMA GEMM with on-the-fly codebook
// decompression; B-fragment of mfma_f32_16x16x32_bf16 = one 16 B codebook
// entry per lane per k-tile. R3: LDS-staged xh tile (kills redundant a-load
// TA traffic), coalesced idx staging + 8-deep gather pipeline, nt gathers,
// separable output FWHT (H8192 = H32 (x) H256).

typedef __attribute__((ext_vector_type(4))) float f32x4;
typedef __attribute__((ext_vector_type(8))) __bf16 bf16x8;
typedef __attribute__((ext_vector_type(4))) __bf16 bf16x4;
typedef __attribute__((ext_vector_type(4))) int i32x4;

#define IN_F 8192
#define OUT_F 8192
#define TOKENS 32
#define KSPLIT 8
#define KCHUNK 1024                   // k per block
#define NSTAGE 4                      // stages of 256 k
#define INV_SQRT_8192 0.011048543456039806f
#define PAD(i) ((i) + ((i) >> 5))

// ---------------- register FWHT-32 ----------------
__device__ inline void fwht32_reg(float* r) {
    #pragma unroll
    for (int h = 1; h < 32; h <<= 1)
        #pragma unroll
        for (int i = 0; i < 32; i += 2 * h)
            #pragma unroll
            for (int j = 0; j < h; ++j) {
                float a = r[i + j], b = r[i + j + h];
                r[i + j] = a + b;
                r[i + j + h] = a - b;
            }
}

// ---------------- full FWHT-8192 in padded LDS, 256 threads ----------------
__device__ inline void fwht8192_lds(float* s, int tid) {
    float r[32];
    int b1 = tid * 32;                       // pass 1: bits 0-4
    #pragma unroll
    for (int j = 0; j < 32; ++j) r[j] = s[PAD(b1 + j)];
    fwht32_reg(r);
    #pragma unroll
    for (int j = 0; j < 32; ++j) s[PAD(b1 + j)] = r[j];
    __syncthreads();
    int b2 = (tid & 31) + (tid >> 5) * 1024; // pass 2: bits 5-9
    #pragma unroll
    for (int j = 0; j < 32; ++j) r[j] = s[PAD(b2 + 32 * j)];
    fwht32_reg(r);
    #pragma unroll
    for (int j = 0; j < 32; ++j) s[PAD(b2 + 32 * j)] = r[j];
    __syncthreads();
    #pragma unroll
    for (int jj = 0; jj < 4; ++jj) {         // pass 3: bits 10-12
        float g[8];
        int b3 = tid * 4 + jj;
        #pragma unroll
        for (int k = 0; k < 8; ++k) g[k] = s[PAD(b3 + 1024 * k)];
        #pragma unroll
        for (int h = 1; h < 8; h <<= 1)
            #pragma unroll
            for (int i = 0; i < 8; i += 2 * h)
                #pragma unroll
                for (int j = 0; j < h; ++j) {
                    float a = g[i + j], b = g[i + j + h];
                    g[i + j] = a + b;
                    g[i + j + h] = a - b;
                }
        #pragma unroll
        for (int k = 0; k < 8; ++k) s[PAD(b3 + 1024 * k)] = g[k];
    }
    __syncthreads();
}

// ---------------- kernel 1: codebook cvt + input FWHT ----------------
__global__ __launch_bounds__(256)
void prep_kernel(const float* __restrict__ cb, __bf16* __restrict__ cbb,
                 const float* __restrict__ x, const float* __restrict__ su,
                 __bf16* __restrict__ xh) {
    __shared__ float s[8192 + 256];
    const int tid = threadIdx.x;
    if (blockIdx.x < 512) {
        int i = blockIdx.x * 256 + tid;
        float4 v = ((const float4*)cb)[i];
        bf16x4 o;
        o[0] = (__bf16)v.x; o[1] = (__bf16)v.y;
        o[2] = (__bf16)v.z; o[3] = (__bf16)v.w;
        ((bf16x4*)cbb)[i] = o;
        return;
    }
    const int t = blockIdx.x - 512;
    #pragma unroll
    for (int i = tid; i < IN_F; i += 256)
        s[PAD(i)] = x[t * IN_F + i] * su[i];
    __syncthreads();
    fwht8192_lds(s, tid);
    #pragma unroll
    for (int i = tid; i < IN_F; i += 256)
        xh[t * IN_F + i] = (__bf16)(s[PAD(i)] * INV_SQRT_8192);
}

// ---------------- kernel 2: z = xh @ W^T, decompressed on the fly ----------
// block = 64 n x 1024 k (ks chunk), 4 waves. 4 stages of 256 k.
// LDS: xh tile 32 tok x 256 k bf16 (16B-chunk swizzled) = 16 KB
//      idx   : 4 waves x 16 rows x 32 ints, row pitch 40 words = 10 KB
__global__ __launch_bounds__(256, 4)
void qgemm_kernel(const int* __restrict__ qidxs,
                  const __bf16* __restrict__ cb,
                  const __bf16* __restrict__ xh,
                  float* __restrict__ zpart) {
    __shared__ __align__(16) unsigned char lds[16384 + 4 * 16 * 40 * 4];
    __bf16* xt = (__bf16*)lds;
    int* it = (int*)(lds + 16384);

    const int ks = blockIdx.x & 7;
    const int nb = blockIdx.x >> 3;
    const int tid = threadIdx.x;
    const int wave = tid >> 6;
    const int lane = tid & 63;
    const int quad = lane >> 4;
    const int l16 = lane & 15;
    const int n = nb * 64 + wave * 16 + l16;

    const bf16x8* cbv = (const bf16x8*)cb;
    f32x4 acc0 = {0.f, 0.f, 0.f, 0.f};
    f32x4 acc1 = {0.f, 0.f, 0.f, 0.f};

    // staging registers
    i32x4 xv[4];   // xh tile chunk (16B each)
    i32x4 iv[2];   // idx chunk

    // preload stage 0
    #pragma unroll
    for (int j = 0; j < 4; ++j) {
        int f = j * 256 + tid, r = f >> 5, c = f & 31;
        xv[j] = *(const i32x4*)(xh + (size_t)r * IN_F + ks * KCHUNK + c * 8);
    }
    #pragma unroll
    for (int i = 0; i < 2; ++i) {
        int r = i * 8 + (lane >> 3), c = lane & 7;
        iv[i] = *(const i32x4*)(qidxs + (size_t)(nb * 64 + wave * 16 + r) * 1024
                                + ks * 128 + c * 4);
    }

    for (int s = 0; s < NSTAGE; ++s) {
        // write staged regs to LDS (swizzled xh; wave-private idx)
        #pragma unroll
        for (int j = 0; j < 4; ++j) {
            int f = j * 256 + tid, r = f >> 5, c = f & 31;
            *(i32x4*)(xt + ((r * 32 + (c ^ (r & 7))) << 3)) = xv[j];
        }
        #pragma unroll
        for (int i = 0; i < 2; ++i) {
            int r = i * 8 + (lane >> 3), c = lane & 7;
            *(i32x4*)(it + wave * 640 + r * 40 + c * 4) = iv[i];
        }
        __syncthreads();

        // this wave's 8 indices (int m = kt*4+quad stored at row*40 + m)
        int myi[8];
        #pragma unroll
        for (int k = 0; k < 8; ++k)
            myi[k] = it[wave * 640 + l16 * 40 + k * 4 + quad];

        // 8 gathers in flight (nt: skip L1 allocate, codebook is L2-resident)
        bf16x8 bf[8];
        #pragma unroll
        for (int k = 0; k < 8; ++k)
            bf[k] = __builtin_nontemporal_load(cbv + myi[k]);

        // prefetch next stage globals AFTER gathers (vmcnt waits keep them live)
        if (s + 1 < NSTAGE) {
            #pragma unroll
            for (int j = 0; j < 4; ++j) {
                int f = j * 256 + tid, r = f >> 5, c = f & 31;
                xv[j] = *(const i32x4*)(xh + (size_t)r * IN_F + ks * KCHUNK
                                        + (s + 1) * 256 + c * 8);
            }
            #pragma unroll
            for (int i = 0; i < 2; ++i) {
                int r = i * 8 + (lane >> 3), c = lane & 7;
                iv[i] = *(const i32x4*)(qidxs
                        + (size_t)(nb * 64 + wave * 16 + r) * 1024
                        + ks * 128 + (s + 1) * 32 + c * 4);
            }
        }

        // 16 MFMAs; a-frags from swizzled LDS
        #pragma unroll
        for (int k = 0; k < 8; ++k) {
            int sw = (((k * 4 + quad) ^ (l16 & 7)) << 3);
            bf16x8 a0 = *(const bf16x8*)(xt + l16 * 256 + sw);
            bf16x8 a1 = *(const bf16x8*)(xt + (l16 + 16) * 256 + sw);
            acc0 = __builtin_amdgcn_mfma_f32_16x16x32_bf16(a0, bf[k], acc0, 0, 0, 0);
            acc1 = __builtin_amdgcn_mfma_f32_16x16x32_bf16(a1, bf[k], acc1, 0, 0, 0);
        }
        __syncthreads();
    }

    // D[m=quad*4+r][n=l16]
    float* zp = zpart + (size_t)ks * TOKENS * OUT_F + n;
    #pragma unroll
    for (int r = 0; r < 4; ++r) {
        zp[(quad * 4 + r) * OUT_F] = acc0[r];
        zp[(16 + quad * 4 + r) * OUT_F] = acc1[r];
    }
}

// ------- kernel 3: phase A out-FWHT: ksum + FWHT-256 (low 8 bits) ----------
__global__ __launch_bounds__(256)
void zsumA_kernel(const float* __restrict__ zpart, float* __restrict__ ztmp) {
    __shared__ float s[1024 + 32];
    const int t = blockIdx.x >> 3, ch = blockIdx.x & 7, tid = threadIdx.x;
    const float* zb = zpart + (size_t)t * OUT_F + ch * 1024 + tid * 4;
    float4 a = {0.f, 0.f, 0.f, 0.f};
    #pragma unroll
    for (int k = 0; k < KSPLIT; ++k) {
        float4 v = *(const float4*)(zb + (size_t)k * TOKENS * OUT_F);
        a.x += v.x; a.y += v.y; a.z += v.z; a.w += v.w;
    }
    s[PAD(4 * tid + 0)] = a.x; s[PAD(4 * tid + 1)] = a.y;
    s[PAD(4 * tid + 2)] = a.z; s[PAD(4 * tid + 3)] = a.w;
    __syncthreads();
    for (int h = 1; h < 256; h <<= 1) {
        #pragma unroll
        for (int b = 0; b < 2; ++b) {
            int p = tid + b * 256;               // pair 0..511
            int g = p >> 7, off = p & 127;
            int i0 = g * 256 + (((off & ~(h - 1)) << 1) | (off & (h - 1)));
            float A = s[PAD(i0)], B = s[PAD(i0 + h)];
            s[PAD(i0)] = A + B; s[PAD(i0 + h)] = A - B;
        }
        __syncthreads();
    }
    float4 o;
    o.x = s[PAD(4 * tid + 0)]; o.y = s[PAD(4 * tid + 1)];
    o.z = s[PAD(4 * tid + 2)]; o.w = s[PAD(4 * tid + 3)];
    *(float4*)(ztmp + (size_t)t * OUT_F + ch * 1024 + tid * 4) = o;
}

// ------- kernel 4: phase B out-FWHT: FWHT-32 (high 5 bits) + scale ---------
__global__ __launch_bounds__(64)
void zsumB_kernel(const float* __restrict__ ztmp, const float* __restrict__ sv,
                  const float* __restrict__ wscale, float* __restrict__ out) {
    const int t = blockIdx.x >> 2;
    const int jl = (blockIdx.x & 3) * 64 + threadIdx.x;   // 0..255
    float r[32];
    #pragma unroll
    for (int jh = 0; jh < 32; ++jh)
        r[jh] = ztmp[(size_t)t * OUT_F + jh * 256 + jl];
    fwht32_reg(r);
    const float sc = INV_SQRT_8192 * wscale[0];
    #pragma unroll
    for (int jh = 0; jh < 32; ++jh)
        out[(size_t)t * OUT_F + jh * 256 + jl] = r[jh] * sc * sv[jh * 256 + jl];
}

extern "C" void kernel_launch(void* const* d_in, const int* in_sizes, int n_in,
                              void* d_out, int out_size, void* d_ws, size_t ws_size,
                              hipStream_t stream) {
    const float* x      = (const float*)d_in[0];   // (32, 8192)
    const float* cb     = (const float*)d_in[1];   // (65536, 8)
    const int*   qidxs  = (const int*)d_in[2];     // (8192, 1024)
    const float* su     = (const float*)d_in[3];   // (8192,)
    const float* sv     = (const float*)d_in[4];   // (8192,)
    const float* wscale = (const float*)d_in[5];   // scalar
    float* out = (float*)d_out;                    // (32, 8192) fp32

    char* ws = (char*)d_ws;
    __bf16* cb_bf16 = (__bf16*)ws;                               // 1 MB
    __bf16* xh      = (__bf16*)(ws + (1u << 20));                // 512 KB
    float*  zpart   = (float*)(ws + (1u << 20) + (512u << 10));  // 8 MB
    float*  ztmp    = (float*)ws;  // reuses cb_bf16 region (done by then)

    hipLaunchKernelGGL(prep_kernel, dim3(544), dim3(256), 0, stream,
                       cb, cb_bf16, x, su, xh);
    hipLaunchKernelGGL(qgemm_kernel, dim3(128 * KSPLIT), dim3(256), 0, stream,
                       qidxs, cb_bf16, xh, zpart);
    hipLaunchKernelGGL(zsumA_kernel, dim3(256), dim3(256), 0, stream,
                       zpart, ztmp);
    hipLaunchKernelGGL(zsumB_kernel, dim3(128), dim3(64), 0, stream,
                       ztmp, sv, wscale, out);
}

// Round 4
// 139.077 us; speedup vs baseline: 1.2218x; 1.2218x over previous
//
#include <hip/hip_runtime.h>
#include <hip/hip_bf16.h>

// QuIP#-style quantized linear. bf16 MFMA GEMM with on-the-fly codebook
// decompression. R4: barrier-free K-loop — xh slice staged to LDS ONCE per
// block (8 waves share), idx + gather software pipeline never drained by
// __syncthreads (the R3 mistake). Gathers issued 3 groups ahead -> ~12 in
// flight/wave, 16 waves/CU -> ~200-400 outstanding VMEM per CU.

typedef __attribute__((ext_vector_type(4))) float f32x4;
typedef __attribute__((ext_vector_type(8))) __bf16 bf16x8;
typedef __attribute__((ext_vector_type(4))) __bf16 bf16x4;
typedef __attribute__((ext_vector_type(4))) int i32x4;

#define IN_F 8192
#define OUT_F 8192
#define TOKENS 32
#define KSPLIT 8
#define INV_SQRT_8192 0.011048543456039806f
#define PAD(i) ((i) + ((i) >> 5))

// ---------------- register FWHT-32 ----------------
__device__ inline void fwht32_reg(float* r) {
    #pragma unroll
    for (int h = 1; h < 32; h <<= 1)
        #pragma unroll
        for (int i = 0; i < 32; i += 2 * h)
            #pragma unroll
            for (int j = 0; j < h; ++j) {
                float a = r[i + j], b = r[i + j + h];
                r[i + j] = a + b;
                r[i + j + h] = a - b;
            }
}

// ---------------- full FWHT-8192 in padded LDS, 256 threads ----------------
__device__ inline void fwht8192_lds(float* s, int tid) {
    float r[32];
    int b1 = tid * 32;                       // pass 1: bits 0-4
    #pragma unroll
    for (int j = 0; j < 32; ++j) r[j] = s[PAD(b1 + j)];
    fwht32_reg(r);
    #pragma unroll
    for (int j = 0; j < 32; ++j) s[PAD(b1 + j)] = r[j];
    __syncthreads();
    int b2 = (tid & 31) + (tid >> 5) * 1024; // pass 2: bits 5-9
    #pragma unroll
    for (int j = 0; j < 32; ++j) r[j] = s[PAD(b2 + 32 * j)];
    fwht32_reg(r);
    #pragma unroll
    for (int j = 0; j < 32; ++j) s[PAD(b2 + 32 * j)] = r[j];
    __syncthreads();
    #pragma unroll
    for (int jj = 0; jj < 4; ++jj) {         // pass 3: bits 10-12
        float g[8];
        int b3 = tid * 4 + jj;
        #pragma unroll
        for (int k = 0; k < 8; ++k) g[k] = s[PAD(b3 + 1024 * k)];
        #pragma unroll
        for (int h = 1; h < 8; h <<= 1)
            #pragma unroll
            for (int i = 0; i < 8; i += 2 * h)
                #pragma unroll
                for (int j = 0; j < h; ++j) {
                    float a = g[i + j], b = g[i + j + h];
                    g[i + j] = a + b;
                    g[i + j + h] = a - b;
                }
        #pragma unroll
        for (int k = 0; k < 8; ++k) s[PAD(b3 + 1024 * k)] = g[k];
    }
    __syncthreads();
}

// ---------------- kernel 1: codebook cvt + input FWHT ----------------
__global__ __launch_bounds__(256)
void prep_kernel(const float* __restrict__ cb, __bf16* __restrict__ cbb,
                 const float* __restrict__ x, const float* __restrict__ su,
                 __bf16* __restrict__ xh) {
    __shared__ float s[8192 + 256];
    const int tid = threadIdx.x;
    if (blockIdx.x < 512) {
        int i = blockIdx.x * 256 + tid;
        float4 v = ((const float4*)cb)[i];
        bf16x4 o;
        o[0] = (__bf16)v.x; o[1] = (__bf16)v.y;
        o[2] = (__bf16)v.z; o[3] = (__bf16)v.w;
        ((bf16x4*)cbb)[i] = o;
        return;
    }
    const int t = blockIdx.x - 512;
    #pragma unroll
    for (int i = tid; i < IN_F; i += 256)
        s[PAD(i)] = x[t * IN_F + i] * su[i];
    __syncthreads();
    fwht8192_lds(s, tid);
    #pragma unroll
    for (int i = tid; i < IN_F; i += 256)
        xh[t * IN_F + i] = (__bf16)(s[PAD(i)] * INV_SQRT_8192);
}

// ---------------- kernel 2: z = xh @ W^T, on-the-fly decompress ------------
// 512 blocks (64 nb x 8 ks) x 512 threads (8 waves). Block = 128 n x 1024 k.
// LDS: xh slice 32 tok x 1024 k bf16 = 64 KB, staged once (1 barrier total).
// Main loop barrier-free: per wave 8 groups x 4 k-tiles; idx loaded 4 groups
// ahead, gathers issued 3 groups ahead (in-order vmcnt: idx older than the
// gathers that consume them, so waits never drain younger gathers).
__global__ __launch_bounds__(512, 4)
void qgemm_kernel(const int* __restrict__ qidxs,
                  const __bf16* __restrict__ cb,
                  const __bf16* __restrict__ xh,
                  float* __restrict__ zpart) {
    __shared__ __align__(16) __bf16 xt[32 * 1024];   // 64 KB
    const int ks = blockIdx.x & 7;
    const int nb = blockIdx.x >> 3;
    const int tid = threadIdx.x;
    const int wave = tid >> 6, lane = tid & 63;
    const int quad = lane >> 4, l16 = lane & 15;
    const int n = nb * 128 + wave * 16 + l16;
    const int* qrow = qidxs + (size_t)n * 1024 + ks * 128;
    const bf16x8* cbv = (const bf16x8*)cb;

    // stage xh slice -> LDS (16B chunks, xor-swizzled for conflict-free reads)
    #pragma unroll
    for (int i = 0; i < 8; ++i) {
        int f = i * 512 + tid, r = f >> 7, c = f & 127;
        i32x4 v = *(const i32x4*)(xh + (size_t)r * IN_F + ks * 1024 + c * 8);
        *(i32x4*)(xt + ((r * 128 + (c ^ (r & 7))) << 3)) = v;
    }
    __syncthreads();    // the only barrier

    f32x4 acc0 = {0.f, 0.f, 0.f, 0.f};
    f32x4 acc1 = {0.f, 0.f, 0.f, 0.f};
    int idx[8][4];
    bf16x8 bfr[8][4];

    // prologue: idx for groups 0..3, gathers for groups 0..2
    #pragma unroll
    for (int g = 0; g < 4; ++g)
        #pragma unroll
        for (int j = 0; j < 4; ++j)
            idx[g][j] = qrow[(g * 4 + j) * 4 + quad];
    #pragma unroll
    for (int g = 0; g < 3; ++g)
        #pragma unroll
        for (int j = 0; j < 4; ++j)
            bfr[g][j] = cbv[idx[g][j]];

    #pragma unroll
    for (int g = 0; g < 8; ++g) {
        if (g + 4 < 8) {
            #pragma unroll
            for (int j = 0; j < 4; ++j)
                idx[g + 4][j] = qrow[((g + 4) * 4 + j) * 4 + quad];
        }
        if (g + 3 < 8) {
            #pragma unroll
            for (int j = 0; j < 4; ++j)
                bfr[g + 3][j] = cbv[idx[g + 3][j]];
        }
        #pragma unroll
        for (int j = 0; j < 4; ++j) {
            const int T = g * 4 + j;
            const int sw = (((4 * T + quad) ^ (l16 & 7)) << 3);
            bf16x8 a0 = *(const bf16x8*)(xt + l16 * 1024 + sw);
            bf16x8 a1 = *(const bf16x8*)(xt + (l16 + 16) * 1024 + sw);
            acc0 = __builtin_amdgcn_mfma_f32_16x16x32_bf16(a0, bfr[g][j], acc0, 0, 0, 0);
            acc1 = __builtin_amdgcn_mfma_f32_16x16x32_bf16(a1, bfr[g][j], acc1, 0, 0, 0);
        }
    }

    // D[m=quad*4+r][n=l16]
    float* zp = zpart + (size_t)ks * TOKENS * OUT_F + n;
    #pragma unroll
    for (int r = 0; r < 4; ++r) {
        zp[(quad * 4 + r) * OUT_F] = acc0[r];
        zp[(16 + quad * 4 + r) * OUT_F] = acc1[r];
    }
}

// ------- kernel 3: phase A out-FWHT: ksum + FWHT-256 (low 8 bits) ----------
__global__ __launch_bounds__(256)
void zsumA_kernel(const float* __restrict__ zpart, float* __restrict__ ztmp) {
    __shared__ float s[1024 + 32];
    const int t = blockIdx.x >> 3, ch = blockIdx.x & 7, tid = threadIdx.x;
    const float* zb = zpart + (size_t)t * OUT_F + ch * 1024 + tid * 4;
    float4 a = {0.f, 0.f, 0.f, 0.f};
    #pragma unroll
    for (int k = 0; k < KSPLIT; ++k) {
        float4 v = *(const float4*)(zb + (size_t)k * TOKENS * OUT_F);
        a.x += v.x; a.y += v.y; a.z += v.z; a.w += v.w;
    }
    s[PAD(4 * tid + 0)] = a.x; s[PAD(4 * tid + 1)] = a.y;
    s[PAD(4 * tid + 2)] = a.z; s[PAD(4 * tid + 3)] = a.w;
    __syncthreads();
    for (int h = 1; h < 256; h <<= 1) {
        #pragma unroll
        for (int b = 0; b < 2; ++b) {
            int p = tid + b * 256;               // pair 0..511
            int g = p >> 7, off = p & 127;
            int i0 = g * 256 + (((off & ~(h - 1)) << 1) | (off & (h - 1)));
            float A = s[PAD(i0)], B = s[PAD(i0 + h)];
            s[PAD(i0)] = A + B; s[PAD(i0 + h)] = A - B;
        }
        __syncthreads();
    }
    float4 o;
    o.x = s[PAD(4 * tid + 0)]; o.y = s[PAD(4 * tid + 1)];
    o.z = s[PAD(4 * tid + 2)]; o.w = s[PAD(4 * tid + 3)];
    *(float4*)(ztmp + (size_t)t * OUT_F + ch * 1024 + tid * 4) = o;
}

// ------- kernel 4: phase B out-FWHT: FWHT-32 (high 5 bits) + scale ---------
__global__ __launch_bounds__(256)
void zsumB_kernel(const float* __restrict__ ztmp, const float* __restrict__ sv,
                  const float* __restrict__ wscale, float* __restrict__ out) {
    const int t = blockIdx.x;
    const int jl = threadIdx.x;                   // 0..255
    float r[32];
    #pragma unroll
    for (int jh = 0; jh < 32; ++jh)
        r[jh] = ztmp[(size_t)t * OUT_F + jh * 256 + jl];
    fwht32_reg(r);
    const float sc = INV_SQRT_8192 * wscale[0];
    #pragma unroll
    for (int jh = 0; jh < 32; ++jh)
        out[(size_t)t * OUT_F + jh * 256 + jl] = r[jh] * sc * sv[jh * 256 + jl];
}

extern "C" void kernel_launch(void* const* d_in, const int* in_sizes, int n_in,
                              void* d_out, int out_size, void* d_ws, size_t ws_size,
                              hipStream_t stream) {
    const float* x      = (const float*)d_in[0];   // (32, 8192)
    const float* cb     = (const float*)d_in[1];   // (65536, 8)
    const int*   qidxs  = (const int*)d_in[2];     // (8192, 1024)
    const float* su     = (const float*)d_in[3];   // (8192,)
    const float* sv     = (const float*)d_in[4];   // (8192,)
    const float* wscale = (const float*)d_in[5];   // scalar
    float* out = (float*)d_out;                    // (32, 8192) fp32

    char* ws = (char*)d_ws;
    __bf16* cb_bf16 = (__bf16*)ws;                               // 1 MB
    __bf16* xh      = (__bf16*)(ws + (1u << 20));                // 512 KB
    float*  zpart   = (float*)(ws + (1u << 20) + (512u << 10));  // 8 MB
    float*  ztmp    = (float*)ws;   // reuses cb_bf16 region (done by then)

    hipLaunchKernelGGL(prep_kernel, dim3(544), dim3(256), 0, stream,
                       cb, cb_bf16, x, su, xh);
    hipLaunchKernelGGL(qgemm_kernel, dim3(64 * KSPLIT), dim3(512), 0, stream,
                       qidxs, cb_bf16, xh, zpart);
    hipLaunchKernelGGL(zsumA_kernel, dim3(256), dim3(256), 0, stream,
                       zpart, ztmp);
    hipLaunchKernelGGL(zsumB_kernel, dim3(TOKENS), dim3(256), 0, stream,
                       ztmp, sv, wscale, out);
}